// Round 6
// baseline (247.638 us; speedup 1.0000x reference)
//
#include <hip/hip_runtime.h>
#include <hip/hip_bf16.h>
#include <stdint.h>

// Problem constants
#define N_NODES 8192
#define N_EDGES 16384
#define N_GRAPHS 512
#define IN_DIM 235
#define H_DIM 64
#define ED_DIM 52
#define HID1 128          // edge-MLP hidden width (W1 rows)
#define KP 256            // K padded 235 -> 256 for MFMA tiling
#define NB 3328           // H_DIM * ED_DIM = P column count (c = h*52 + d !)
#define NBE 3456          // NB + 64 (root) + 64 (bc) live GEMM columns
#define NBP 3584          // padded to 14 x 256 tiles (cols 3456..3583 zero)

typedef __bf16 bf16x8 __attribute__((ext_vector_type(8)));
typedef float f32x4 __attribute__((ext_vector_type(4)));

static __device__ inline unsigned short f2bf(float f) {
    union { float f; unsigned u; } v; v.f = f;
    unsigned r = v.u + 0x7FFFu + ((v.u >> 16) & 1u);   // RNE
    return (unsigned short)(r >> 16);
}

// ---------------------------------------------------------------------------
// K0a: compose edge-MLP weights. COLUMN ORDER c = h*52 + d (h-major) so that
// the edge kernel reads each lane's 52 d-values as 104 CONTIGUOUS bytes.
// Bt[c=(h*52+d)][i] = sum_k W2[(i*64+h)*128+k] * W1[k*52+d]
// Block (i, by): h in [by*16, by*16+16), all d. W1 staged transposed [d][k].
__global__ __launch_bounds__(256) void k_build_bt(const float* __restrict__ W1,
                                                  const float* __restrict__ W2,
                                                  unsigned short* __restrict__ Bt) {
    __shared__ float w1s[ED_DIM * HID1];      // [d][k]  26.6 KB
    __shared__ float w2s[16 * 132];           // [hh][k] padded, 8.4 KB
    const int i = blockIdx.x;                 // 0..234
    const int by = blockIdx.y;                // 0..3 -> h base by*16
    const int t = threadIdx.x;
    for (int j = t; j < ED_DIM * HID1; j += 256) {
        const int d = j >> 7, k = j & 127;
        w1s[j] = W1[k * ED_DIM + d];
    }
    const float* w2src = W2 + ((size_t)i * 64 + by * 16) * HID1;
    for (int j = t; j < 16 * HID1; j += 256) w2s[(j >> 7) * 132 + (j & 127)] = w2src[j];
    __syncthreads();
    for (int pl = t; pl < 832; pl += 256) {       // 832 = 16 h x 52 d
        const int hh = pl / 52, d = pl - hh * 52;
        const float4* w1v = (const float4*)&w1s[d * HID1];
        const float4* w2v = (const float4*)&w2s[hh * 132];
        float acc = 0.f;
        #pragma unroll
        for (int k4 = 0; k4 < HID1 / 4; ++k4) {
            const float4 a = w1v[k4], b = w2v[k4];
            acc += a.x * b.x + a.y * b.y + a.z * b.z + a.w * b.w;
        }
        const int p = by * 832 + pl;              // = (by*16+hh)*52 + d
        Bt[(size_t)p * KP + i] = f2bf(acc);
    }
}

// K0c: extra GEMM columns, bc computed inline:
// col 3328+j (j<64) = root[:,j]; col 3392+j = bc[:,j] = b2 + W2 @ b1 slice.
__global__ __launch_bounds__(256) void k_build_ext(const float* __restrict__ root,
                                                   const float* __restrict__ W2,
                                                   const float* __restrict__ b1,
                                                   const float* __restrict__ b2,
                                                   unsigned short* __restrict__ Bt) {
    const int j = blockIdx.x;        // 0..127
    const int i = threadIdx.x;       // 0..255
    if (i >= IN_DIM) return;
    float v;
    if (j < 64) {
        v = root[i * H_DIM + j];
    } else {
        const int jj = i * H_DIM + (j - 64);
        float acc = b2[jj];
        const float* w = W2 + (size_t)jj * HID1;
        #pragma unroll 8
        for (int k = 0; k < HID1; ++k) acc += w[k] * b1[k];
        v = acc;
    }
    Bt[(size_t)(NB + j) * KP + i] = f2bf(v);
}

// K1: x (fp32, [8192,235]) -> A (bf16, [8192,256] zero-padded)
__global__ __launch_bounds__(256) void k_build_a(const float* __restrict__ x,
                                                 unsigned short* __restrict__ A) {
    const int j = blockIdx.x * 256 + threadIdx.x;
    const int n = j >> 8, i = j & 255;
    A[j] = (i < IN_DIM) ? f2bf(x[n * IN_DIM + i]) : (unsigned short)0;
}

// ---------------------------------------------------------------------------
// K2: [8192,256] x [256,3584] GEMM, 256x256 tiles (512 thr, 8 waves, each
// 128x64). 1-D grid of 448 with XCD-aware remap (lin%8 = XCD heuristic):
// XCD x owns m-tiles {x, x+8, x+16, x+24} x all 14 n-tiles -> per-XCD working
// set 0.5 MB A + 1.8 MB Bt < 4 MB L2 (was: every XCD streaming all 5.9 MB).
// Prefetch-after-barrier dbuf, XOR source swizzle, swapped MFMA operands
// (transposed D -> packed row-major stores). n-tile 13 = ext tile:
// cols 3328..3391 -> agg(+conv_b), 3392..3455 -> xb2, rest garbage (skipped).
__global__ __launch_bounds__(512, 2) void k_gemm(const unsigned short* __restrict__ A,
                                                 const unsigned short* __restrict__ Bt,
                                                 unsigned short* __restrict__ P,
                                                 float* __restrict__ agg,
                                                 float* __restrict__ xb2,
                                                 const float* __restrict__ conv_b) {
    __shared__ unsigned short As[2 * 256 * 32];   // 32 KB
    __shared__ unsigned short Bs[2 * 256 * 32];   // 32 KB
    const int t = threadIdx.x;
    const int lin = blockIdx.x;                   // 0..447
    const int xcd = lin & 7, bi = lin >> 3;       // 56 blocks per XCD
    const int mt = (bi / 14) * 8 + xcd;           // 0..31
    const int nt = bi % 14;                       // 0..13
    const int m0 = mt * 256, n0 = nt * 256;
    const int wid = t >> 6, lane = t & 63;
    const int wm = wid & 1;          // 0..1 : 128-row half
    const int wn = wid >> 1;         // 0..3 : 64-col quarter
    const int q = lane >> 4, r16 = lane & 15;

    f32x4 acc[8][4] = {};

    auto stage = [&](int k0, int buf) {
        #pragma unroll
        for (int r = 0; r < 2; ++r) {
            const int idx = r * 512 + t;              // 0..1023 physical 16B slots
            const int row = idx >> 2;                 // 0..255
            const int lgrp = ((idx & 3) ^ ((row >> 1) & 3)) * 8;  // logical k-chunk
            const unsigned short* ga = &A[(size_t)(m0 + row) * KP + k0 + lgrp];
            const unsigned short* gb = &Bt[(size_t)(n0 + row) * KP + k0 + lgrp];
            char* la = (char*)As + buf * 16384 + r * 8192 + wid * 1024;
            char* lb = (char*)Bs + buf * 16384 + r * 8192 + wid * 1024;
            __builtin_amdgcn_global_load_lds(
                (const __attribute__((address_space(1))) unsigned int*)ga,
                (__attribute__((address_space(3))) unsigned int*)la, 16, 0, 0);
            __builtin_amdgcn_global_load_lds(
                (const __attribute__((address_space(1))) unsigned int*)gb,
                (__attribute__((address_space(3))) unsigned int*)lb, 16, 0, 0);
        }
    };

    stage(0, 0);
    const int pcq = (q ^ ((r16 >> 1) & 3)) * 8;       // physical chunk for logical q
    #pragma unroll
    for (int it = 0; it < 8; ++it) {
        __syncthreads();                              // drains prefetch for buf[it&1]
        if (it < 7) stage((it + 1) * 32, (it + 1) & 1);
        const int bo = (it & 1) * 8192;               // buffer offset in shorts
        bf16x8 af[8], bfr[4];
        #pragma unroll
        for (int mi = 0; mi < 8; ++mi)
            af[mi] = *(const bf16x8*)(&As[bo + (wm * 128 + mi * 16 + r16) * 32 + pcq]);
        #pragma unroll
        for (int ni = 0; ni < 4; ++ni)
            bfr[ni] = *(const bf16x8*)(&Bs[bo + (wn * 64 + ni * 16 + r16) * 32 + pcq]);
        #pragma unroll
        for (int mi = 0; mi < 8; ++mi)
            #pragma unroll
            for (int ni = 0; ni < 4; ++ni)
                acc[mi][ni] = __builtin_amdgcn_mfma_f32_16x16x32_bf16(
                    bfr[ni], af[mi], acc[mi][ni], 0, 0, 0);   // transposed D
    }

    // Transposed D: lane (q,r16) holds rows m = mi*16+r16, cols n = ni*16+q*4..+3
    if (n0 < NB) {
        #pragma unroll
        for (int mi = 0; mi < 8; ++mi)
            #pragma unroll
            for (int ni = 0; ni < 4; ++ni) {
                const int row = m0 + wm * 128 + mi * 16 + r16;
                const int col = n0 + wn * 64 + ni * 16 + q * 4;
                union { unsigned short us[4]; uint2 u2; } pk;
                #pragma unroll
                for (int rr = 0; rr < 4; ++rr) pk.us[rr] = f2bf(acc[mi][ni][rr]);
                *(uint2*)(&P[(size_t)row * NB + col]) = pk.u2;
            }
    } else if (wn < 2) {
        #pragma unroll
        for (int mi = 0; mi < 8; ++mi)
            #pragma unroll
            for (int ni = 0; ni < 4; ++ni) {
                const int row = m0 + wm * 128 + mi * 16 + r16;
                const int cl = ni * 16 + q * 4;       // 0..63 within the half
                if (wn == 0) {
                    const float4 cb = *(const float4*)&conv_b[cl];
                    float4 v;
                    v.x = acc[mi][ni][0] + cb.x; v.y = acc[mi][ni][1] + cb.y;
                    v.z = acc[mi][ni][2] + cb.z; v.w = acc[mi][ni][3] + cb.w;
                    *(float4*)(&agg[row * H_DIM + cl]) = v;
                } else {
                    float4 v;
                    v.x = acc[mi][ni][0]; v.y = acc[mi][ni][1];
                    v.z = acc[mi][ni][2]; v.w = acc[mi][ni][3];
                    *(float4*)(&xb2[row * H_DIM + cl]) = v;
                }
            }
    }
}

// ---------------------------------------------------------------------------
// K4: per edge (one wave, lane=h). With the h-major P layout, lane h's 52
// d-values are 104 CONTIGUOUS bytes at P + s*3328 + h*52: 13 aligned uint2
// loads, all in flight, fully coalesced across the wave (6656 B/row).
__global__ __launch_bounds__(256) void k_edge(const int* __restrict__ ei,
                                              const float* __restrict__ ea,
                                              const unsigned short* __restrict__ P,
                                              const float* __restrict__ xb2,
                                              float* __restrict__ agg) {
    const int e = (blockIdx.x * 256 + threadIdx.x) >> 6;
    const int h = threadIdx.x & 63;
    if (e >= N_EDGES) return;
    const int s = ei[e], dst = ei[N_EDGES + e];
    const uint2* Pr = (const uint2*)(P + (size_t)s * NB + h * ED_DIM);
    const float4* ev = (const float4*)(ea + (size_t)e * ED_DIM);

    uint2 pv[13];
    #pragma unroll
    for (int j = 0; j < 13; ++j) pv[j] = Pr[j];
    float4 eav[13];
    #pragma unroll
    for (int j = 0; j < 13; ++j) eav[j] = ev[j];

    float acc = xb2[s * H_DIM + h];
    #pragma unroll
    for (int j = 0; j < 13; ++j) {
        union { unsigned u; float f; } a0, a1, b0, b1;
        a0.u = pv[j].x << 16; a1.u = pv[j].x & 0xffff0000u;
        b0.u = pv[j].y << 16; b1.u = pv[j].y & 0xffff0000u;
        acc += eav[j].x * a0.f + eav[j].y * a1.f
             + eav[j].z * b0.f + eav[j].w * b1.f;
    }
    atomicAdd(&agg[dst * H_DIM + h], acc);
}

// K5: out = relu(agg); mean-pool accumulate per graph
__global__ __launch_bounds__(256) void k_pool(const float* __restrict__ agg,
                                              const int* __restrict__ batch,
                                              float* __restrict__ psum,
                                              float* __restrict__ pcnt) {
    const int n = (blockIdx.x * 256 + threadIdx.x) >> 6;
    const int h = threadIdx.x & 63;
    if (n >= N_NODES) return;
    const float v = fmaxf(agg[n * H_DIM + h], 0.f);
    const int g = batch[n];
    atomicAdd(&psum[g * H_DIM + h], v);
    if (h == 0) atomicAdd(&pcnt[g], 1.0f);
}

// K6: MLP head, one block per graph
__global__ __launch_bounds__(256) void k_head(const float* __restrict__ psum,
                                              const float* __restrict__ pcnt,
                                              const float* __restrict__ fw1, const float* __restrict__ fb1,
                                              const float* __restrict__ fw2, const float* __restrict__ fb2,
                                              const float* __restrict__ fw3, const float* __restrict__ fb3,
                                              const float* __restrict__ fw4, const float* __restrict__ fb4,
                                              float* __restrict__ out) {
    __shared__ float sp[64], s1[128], s2[256], s3[128];
    const int g = blockIdx.x, t = threadIdx.x;
    if (t < 64) sp[t] = psum[g * 64 + t] / fmaxf(pcnt[g], 1.0f);
    __syncthreads();
    if (t < 128) {
        float a = fb1[t];
        const float* w = fw1 + t * 64;
        #pragma unroll 8
        for (int k = 0; k < 64; ++k) a += sp[k] * w[k];
        s1[t] = fmaxf(a, 0.f);
    }
    __syncthreads();
    {
        float a = fb2[t];
        const float* w = fw2 + t * 128;
        #pragma unroll 8
        for (int k = 0; k < 128; ++k) a += s1[k] * w[k];
        s2[t] = fmaxf(a, 0.f);
    }
    __syncthreads();
    if (t < 128) {
        float a = fb3[t];
        const float* w = fw3 + t * 256;
        #pragma unroll 8
        for (int k = 0; k < 256; ++k) a += s2[k] * w[k];
        s3[t] = fmaxf(a, 0.f);
    }
    __syncthreads();
    if (t < 64) {
        float p = s3[t] * fw4[t] + s3[t + 64] * fw4[t + 64];
        #pragma unroll
        for (int off = 32; off > 0; off >>= 1) p += __shfl_down(p, off);
        if (t == 0) out[g] = p + fb4[0];
    }
}

// ---------------------------------------------------------------------------
extern "C" void kernel_launch(void* const* d_in, const int* in_sizes, int n_in,
                              void* d_out, int out_size, void* d_ws, size_t ws_size,
                              hipStream_t stream) {
    const float* x      = (const float*)d_in[0];
    const int*   ei     = (const int*)d_in[1];
    const float* ea     = (const float*)d_in[2];
    const int*   batch  = (const int*)d_in[3];
    const float* W1     = (const float*)d_in[4];
    const float* b1     = (const float*)d_in[5];
    const float* W2     = (const float*)d_in[6];
    const float* b2     = (const float*)d_in[7];
    const float* root   = (const float*)d_in[8];
    const float* conv_b = (const float*)d_in[9];
    const float* fw1 = (const float*)d_in[10]; const float* fb1 = (const float*)d_in[11];
    const float* fw2 = (const float*)d_in[12]; const float* fb2 = (const float*)d_in[13];
    const float* fw3 = (const float*)d_in[14]; const float* fb3 = (const float*)d_in[15];
    const float* fw4 = (const float*)d_in[16]; const float* fb4 = (const float*)d_in[17];
    float* out = (float*)d_out;

    char* ws = (char*)d_ws;
    // workspace layout (16B-aligned), total ~64.9 MB
    unsigned short* A   = (unsigned short*)(ws);             // 8192*256*2   = 4,194,304
    unsigned short* Bt  = (unsigned short*)(ws + 4194304);   // 3584*256*2   = 1,835,008
    unsigned short* P   = (unsigned short*)(ws + 6029312);   // 8192*3328*2  = 54,525,952
    float* agg  = (float*)(ws + 60555264);                   // 8192*64*4    = 2,097,152
    float* xb2  = (float*)(ws + 62652416);                   // 8192*64*4    = 2,097,152
    float* psum = (float*)(ws + 64749568);                   // 512*64*4     = 131,072
    float* pcnt = (float*)(ws + 64880640);                   // 512*4        = 2,048

    // Bt must start zeroed (pad cols i>=235 and rows >=3456); psum/pcnt -> one memset
    hipMemsetAsync(Bt, 0, (size_t)NBP * KP * sizeof(unsigned short), stream);
    hipMemsetAsync(psum, 0, (size_t)(N_GRAPHS * H_DIM + N_GRAPHS) * sizeof(float), stream);

    k_build_bt<<<dim3(IN_DIM, 4), dim3(256), 0, stream>>>(W1, W2, Bt);
    k_build_ext<<<dim3(128), dim3(256), 0, stream>>>(root, W2, b1, b2, Bt);
    k_build_a<<<dim3(N_NODES), dim3(256), 0, stream>>>(x, A);
    k_gemm<<<dim3(448), dim3(512), 0, stream>>>(A, Bt, P, agg, xb2, conv_b);
    k_edge<<<dim3(N_EDGES / 4), dim3(256), 0, stream>>>(ei, ea, P, xb2, agg);
    k_pool<<<dim3(N_NODES / 4), dim3(256), 0, stream>>>(agg, batch, psum, pcnt);
    k_head<<<dim3(N_GRAPHS), dim3(256), 0, stream>>>(psum, pcnt, fw1, fb1, fw2, fb2, fw3, fb3, fw4, fb4, out);
}

// Round 7
// 208.065 us; speedup vs baseline: 1.1902x; 1.1902x over previous
//
#include <hip/hip_runtime.h>
#include <hip/hip_bf16.h>
#include <stdint.h>

// Problem constants
#define N_NODES 8192
#define N_EDGES 16384
#define N_GRAPHS 512
#define IN_DIM 235
#define H_DIM 64
#define ED_DIM 52
#define HID1 128          // edge-MLP hidden width (W1 rows)
#define KP 256            // K padded 235 -> 256 for MFMA tiling
#define NB 3328           // H_DIM * ED_DIM = P column count (c = h*52 + d)
#define NBE 3456          // NB + 64 (root) + 64 (bc) live GEMM columns
#define NBP 3584          // padded to 14 x 256 tiles (cols 3456..3583 zero)

typedef __bf16 bf16x8 __attribute__((ext_vector_type(8)));
typedef float f32x4 __attribute__((ext_vector_type(4)));

static __device__ inline unsigned short f2bf(float f) {
    union { float f; unsigned u; } v; v.f = f;
    unsigned r = v.u + 0x7FFFu + ((v.u >> 16) & 1u);   // RNE
    return (unsigned short)(r >> 16);
}

// ---------------------------------------------------------------------------
// K0a: compose edge-MLP weights, h-major columns: Bt[c=(h*52+d)][i] =
// sum_k W2[(i*64+h)*128+k] * W1[k*52+d].
// Block (i, by): h in [by*16, by*16+16). Thread (hh=t&15, dq=t>>4) handles
// d in {dq, dq+16, dq+32, dq+48} & [0,52).
// Bank analysis (pad 132): w1 read = 4 distinct rows/wave, 16-lane broadcast
// groups at start banks 4*dq (disjoint) -> conflict-free; w2 read = hh*132 ->
// 2-way (free). r6's mapping had 52 distinct w1 rows all at bank group 0 ->
// 23.5M conflicts, 60 us. Both staging loops globally coalesced.
__global__ __launch_bounds__(256) void k_build_bt(const float* __restrict__ W1,
                                                  const float* __restrict__ W2,
                                                  unsigned short* __restrict__ Bt) {
    __shared__ float w1s[ED_DIM * 132];       // [d][k] padded, 27.5 KB
    __shared__ float w2s[16 * 132];           // [hh][k] padded, 8.4 KB
    const int i = blockIdx.x;                 // 0..234
    const int by = blockIdx.y;                // 0..3 -> h base by*16
    const int t = threadIdx.x;
    for (int j = t; j < ED_DIM * HID1; j += 256) {
        const int k = j / ED_DIM, d = j - k * ED_DIM;   // j linear in W1
        w1s[d * 132 + k] = W1[j];
    }
    const float* w2src = W2 + ((size_t)i * 64 + by * 16) * HID1;
    for (int j = t; j < 16 * HID1; j += 256) w2s[(j >> 7) * 132 + (j & 127)] = w2src[j];
    __syncthreads();
    const int hh = t & 15, dq = t >> 4;
    const float4* w2v = (const float4*)&w2s[hh * 132];
    #pragma unroll
    for (int m = 0; m < 4; ++m) {
        const int d = dq + m * 16;
        if (d >= ED_DIM) break;
        const float4* w1v = (const float4*)&w1s[d * 132];
        float acc = 0.f;
        #pragma unroll
        for (int k4 = 0; k4 < HID1 / 4; ++k4) {
            const float4 a = w1v[k4], b = w2v[k4];
            acc += a.x * b.x + a.y * b.y + a.z * b.z + a.w * b.w;
        }
        const int p = (by * 16 + hh) * ED_DIM + d;
        Bt[(size_t)p * KP + i] = f2bf(acc);
    }
}

// K0c: extra GEMM columns, bc computed inline:
// col 3328+j (j<64) = root[:,j]; col 3392+j = bc[:,j] = b2 + W2 @ b1 slice.
__global__ __launch_bounds__(256) void k_build_ext(const float* __restrict__ root,
                                                   const float* __restrict__ W2,
                                                   const float* __restrict__ b1,
                                                   const float* __restrict__ b2,
                                                   unsigned short* __restrict__ Bt) {
    const int j = blockIdx.x;        // 0..127
    const int i = threadIdx.x;       // 0..255
    if (i >= IN_DIM) return;
    float v;
    if (j < 64) {
        v = root[i * H_DIM + j];
    } else {
        const int jj = i * H_DIM + (j - 64);
        float acc = b2[jj];
        const float* w = W2 + (size_t)jj * HID1;
        #pragma unroll 8
        for (int k = 0; k < HID1; ++k) acc += w[k] * b1[k];
        v = acc;
    }
    Bt[(size_t)(NB + j) * KP + i] = f2bf(v);
}

// K1: x (fp32, [8192,235]) -> A (bf16, [8192,256] zero-padded)
__global__ __launch_bounds__(256) void k_build_a(const float* __restrict__ x,
                                                 unsigned short* __restrict__ A) {
    const int j = blockIdx.x * 256 + threadIdx.x;
    const int n = j >> 8, i = j & 255;
    A[j] = (i < IN_DIM) ? f2bf(x[n * IN_DIM + i]) : (unsigned short)0;
}

// ---------------------------------------------------------------------------
// K2: [8192,256] x [256,3584] GEMM, 256x256 tiles (512 thr, 8 waves, each
// 128x64). 1-D grid of 448 with XCD-aware remap (lin%8 = XCD heuristic):
// XCD x owns m-tiles {x, x+8, x+16, x+24} x all 14 n-tiles -> per-XCD working
// set 0.5 MB A + 1.8 MB Bt < 4 MB L2. Prefetch-after-barrier dbuf, XOR source
// swizzle, swapped MFMA operands (transposed D -> packed row-major stores).
// n-tile 13 = ext tile: cols 3328..3391 -> agg(+conv_b), 3392..3455 -> xb2.
__global__ __launch_bounds__(512, 2) void k_gemm(const unsigned short* __restrict__ A,
                                                 const unsigned short* __restrict__ Bt,
                                                 unsigned short* __restrict__ P,
                                                 float* __restrict__ agg,
                                                 float* __restrict__ xb2,
                                                 const float* __restrict__ conv_b) {
    __shared__ unsigned short As[2 * 256 * 32];   // 32 KB
    __shared__ unsigned short Bs[2 * 256 * 32];   // 32 KB
    const int t = threadIdx.x;
    const int lin = blockIdx.x;                   // 0..447
    const int xcd = lin & 7, bi = lin >> 3;       // 56 blocks per XCD
    const int mt = (bi / 14) * 8 + xcd;           // 0..31
    const int nt = bi % 14;                       // 0..13
    const int m0 = mt * 256, n0 = nt * 256;
    const int wid = t >> 6, lane = t & 63;
    const int wm = wid & 1;          // 0..1 : 128-row half
    const int wn = wid >> 1;         // 0..3 : 64-col quarter
    const int q = lane >> 4, r16 = lane & 15;

    f32x4 acc[8][4] = {};

    auto stage = [&](int k0, int buf) {
        #pragma unroll
        for (int r = 0; r < 2; ++r) {
            const int idx = r * 512 + t;              // 0..1023 physical 16B slots
            const int row = idx >> 2;                 // 0..255
            const int lgrp = ((idx & 3) ^ ((row >> 1) & 3)) * 8;  // logical k-chunk
            const unsigned short* ga = &A[(size_t)(m0 + row) * KP + k0 + lgrp];
            const unsigned short* gb = &Bt[(size_t)(n0 + row) * KP + k0 + lgrp];
            char* la = (char*)As + buf * 16384 + r * 8192 + wid * 1024;
            char* lb = (char*)Bs + buf * 16384 + r * 8192 + wid * 1024;
            __builtin_amdgcn_global_load_lds(
                (const __attribute__((address_space(1))) unsigned int*)ga,
                (__attribute__((address_space(3))) unsigned int*)la, 16, 0, 0);
            __builtin_amdgcn_global_load_lds(
                (const __attribute__((address_space(1))) unsigned int*)gb,
                (__attribute__((address_space(3))) unsigned int*)lb, 16, 0, 0);
        }
    };

    stage(0, 0);
    const int pcq = (q ^ ((r16 >> 1) & 3)) * 8;       // physical chunk for logical q
    #pragma unroll
    for (int it = 0; it < 8; ++it) {
        __syncthreads();                              // drains prefetch for buf[it&1]
        if (it < 7) stage((it + 1) * 32, (it + 1) & 1);
        const int bo = (it & 1) * 8192;               // buffer offset in shorts
        bf16x8 af[8], bfr[4];
        #pragma unroll
        for (int mi = 0; mi < 8; ++mi)
            af[mi] = *(const bf16x8*)(&As[bo + (wm * 128 + mi * 16 + r16) * 32 + pcq]);
        #pragma unroll
        for (int ni = 0; ni < 4; ++ni)
            bfr[ni] = *(const bf16x8*)(&Bs[bo + (wn * 64 + ni * 16 + r16) * 32 + pcq]);
        #pragma unroll
        for (int mi = 0; mi < 8; ++mi)
            #pragma unroll
            for (int ni = 0; ni < 4; ++ni)
                acc[mi][ni] = __builtin_amdgcn_mfma_f32_16x16x32_bf16(
                    bfr[ni], af[mi], acc[mi][ni], 0, 0, 0);   // transposed D
    }

    // Transposed D: lane (q,r16) holds rows m = mi*16+r16, cols n = ni*16+q*4..+3
    if (n0 < NB) {
        #pragma unroll
        for (int mi = 0; mi < 8; ++mi)
            #pragma unroll
            for (int ni = 0; ni < 4; ++ni) {
                const int row = m0 + wm * 128 + mi * 16 + r16;
                const int col = n0 + wn * 64 + ni * 16 + q * 4;
                union { unsigned short us[4]; uint2 u2; } pk;
                #pragma unroll
                for (int rr = 0; rr < 4; ++rr) pk.us[rr] = f2bf(acc[mi][ni][rr]);
                *(uint2*)(&P[(size_t)row * NB + col]) = pk.u2;
            }
    } else if (wn < 2) {
        #pragma unroll
        for (int mi = 0; mi < 8; ++mi)
            #pragma unroll
            for (int ni = 0; ni < 4; ++ni) {
                const int row = m0 + wm * 128 + mi * 16 + r16;
                const int cl = ni * 16 + q * 4;       // 0..63 within the half
                if (wn == 0) {
                    const float4 cb = *(const float4*)&conv_b[cl];
                    float4 v;
                    v.x = acc[mi][ni][0] + cb.x; v.y = acc[mi][ni][1] + cb.y;
                    v.z = acc[mi][ni][2] + cb.z; v.w = acc[mi][ni][3] + cb.w;
                    *(float4*)(&agg[row * H_DIM + cl]) = v;
                } else {
                    float4 v;
                    v.x = acc[mi][ni][0]; v.y = acc[mi][ni][1];
                    v.z = acc[mi][ni][2]; v.w = acc[mi][ni][3];
                    *(float4*)(&xb2[row * H_DIM + cl]) = v;
                }
            }
    }
}

// ---------------------------------------------------------------------------
// K4: per edge (one wave, lane=h). h-major P: lane h's 52 d-values are 104
// contiguous bytes at P + s*3328 + h*52 -> 13 aligned uint2 loads, all in
// flight, fully coalesced across the wave.
__global__ __launch_bounds__(256) void k_edge(const int* __restrict__ ei,
                                              const float* __restrict__ ea,
                                              const unsigned short* __restrict__ P,
                                              const float* __restrict__ xb2,
                                              float* __restrict__ agg) {
    const int e = (blockIdx.x * 256 + threadIdx.x) >> 6;
    const int h = threadIdx.x & 63;
    if (e >= N_EDGES) return;
    const int s = ei[e], dst = ei[N_EDGES + e];
    const uint2* Pr = (const uint2*)(P + (size_t)s * NB + h * ED_DIM);
    const float4* ev = (const float4*)(ea + (size_t)e * ED_DIM);

    uint2 pv[13];
    #pragma unroll
    for (int j = 0; j < 13; ++j) pv[j] = Pr[j];
    float4 eav[13];
    #pragma unroll
    for (int j = 0; j < 13; ++j) eav[j] = ev[j];

    float acc = xb2[s * H_DIM + h];
    #pragma unroll
    for (int j = 0; j < 13; ++j) {
        union { unsigned u; float f; } a0, a1, b0, b1;
        a0.u = pv[j].x << 16; a1.u = pv[j].x & 0xffff0000u;
        b0.u = pv[j].y << 16; b1.u = pv[j].y & 0xffff0000u;
        acc += eav[j].x * a0.f + eav[j].y * a1.f
             + eav[j].z * b0.f + eav[j].w * b1.f;
    }
    atomicAdd(&agg[dst * H_DIM + h], acc);
}

// K5: out = relu(agg); mean-pool accumulate per graph
__global__ __launch_bounds__(256) void k_pool(const float* __restrict__ agg,
                                              const int* __restrict__ batch,
                                              float* __restrict__ psum,
                                              float* __restrict__ pcnt) {
    const int n = (blockIdx.x * 256 + threadIdx.x) >> 6;
    const int h = threadIdx.x & 63;
    if (n >= N_NODES) return;
    const float v = fmaxf(agg[n * H_DIM + h], 0.f);
    const int g = batch[n];
    atomicAdd(&psum[g * H_DIM + h], v);
    if (h == 0) atomicAdd(&pcnt[g], 1.0f);
}

// K6: MLP head, one block per graph
__global__ __launch_bounds__(256) void k_head(const float* __restrict__ psum,
                                              const float* __restrict__ pcnt,
                                              const float* __restrict__ fw1, const float* __restrict__ fb1,
                                              const float* __restrict__ fw2, const float* __restrict__ fb2,
                                              const float* __restrict__ fw3, const float* __restrict__ fb3,
                                              const float* __restrict__ fw4, const float* __restrict__ fb4,
                                              float* __restrict__ out) {
    __shared__ float sp[64], s1[128], s2[256], s3[128];
    const int g = blockIdx.x, t = threadIdx.x;
    if (t < 64) sp[t] = psum[g * 64 + t] / fmaxf(pcnt[g], 1.0f);
    __syncthreads();
    if (t < 128) {
        float a = fb1[t];
        const float* w = fw1 + t * 64;
        #pragma unroll 8
        for (int k = 0; k < 64; ++k) a += sp[k] * w[k];
        s1[t] = fmaxf(a, 0.f);
    }
    __syncthreads();
    {
        float a = fb2[t];
        const float* w = fw2 + t * 128;
        #pragma unroll 8
        for (int k = 0; k < 128; ++k) a += s1[k] * w[k];
        s2[t] = fmaxf(a, 0.f);
    }
    __syncthreads();
    if (t < 128) {
        float a = fb3[t];
        const float* w = fw3 + t * 256;
        #pragma unroll 8
        for (int k = 0; k < 256; ++k) a += s2[k] * w[k];
        s3[t] = fmaxf(a, 0.f);
    }
    __syncthreads();
    if (t < 64) {
        float p = s3[t] * fw4[t] + s3[t + 64] * fw4[t + 64];
        #pragma unroll
        for (int off = 32; off > 0; off >>= 1) p += __shfl_down(p, off);
        if (t == 0) out[g] = p + fb4[0];
    }
}

// ---------------------------------------------------------------------------
extern "C" void kernel_launch(void* const* d_in, const int* in_sizes, int n_in,
                              void* d_out, int out_size, void* d_ws, size_t ws_size,
                              hipStream_t stream) {
    const float* x      = (const float*)d_in[0];
    const int*   ei     = (const int*)d_in[1];
    const float* ea     = (const float*)d_in[2];
    const int*   batch  = (const int*)d_in[3];
    const float* W1     = (const float*)d_in[4];
    const float* b1     = (const float*)d_in[5];
    const float* W2     = (const float*)d_in[6];
    const float* b2     = (const float*)d_in[7];
    const float* root   = (const float*)d_in[8];
    const float* conv_b = (const float*)d_in[9];
    const float* fw1 = (const float*)d_in[10]; const float* fb1 = (const float*)d_in[11];
    const float* fw2 = (const float*)d_in[12]; const float* fb2 = (const float*)d_in[13];
    const float* fw3 = (const float*)d_in[14]; const float* fb3 = (const float*)d_in[15];
    const float* fw4 = (const float*)d_in[16]; const float* fb4 = (const float*)d_in[17];
    float* out = (float*)d_out;

    char* ws = (char*)d_ws;
    // workspace layout (16B-aligned), total ~64.9 MB
    unsigned short* A   = (unsigned short*)(ws);             // 8192*256*2   = 4,194,304
    unsigned short* Bt  = (unsigned short*)(ws + 4194304);   // 3584*256*2   = 1,835,008
    unsigned short* P   = (unsigned short*)(ws + 6029312);   // 8192*3328*2  = 54,525,952
    float* agg  = (float*)(ws + 60555264);                   // 8192*64*4    = 2,097,152
    float* xb2  = (float*)(ws + 62652416);                   // 8192*64*4    = 2,097,152
    float* psum = (float*)(ws + 64749568);                   // 512*64*4     = 131,072
    float* pcnt = (float*)(ws + 64880640);                   // 512*4        = 2,048

    // Bt must start zeroed (pad cols i>=235 and rows >=3456); psum/pcnt -> one memset
    hipMemsetAsync(Bt, 0, (size_t)NBP * KP * sizeof(unsigned short), stream);
    hipMemsetAsync(psum, 0, (size_t)(N_GRAPHS * H_DIM + N_GRAPHS) * sizeof(float), stream);

    k_build_bt<<<dim3(IN_DIM, 4), dim3(256), 0, stream>>>(W1, W2, Bt);
    k_build_ext<<<dim3(128), dim3(256), 0, stream>>>(root, W2, b1, b2, Bt);
    k_build_a<<<dim3(N_NODES), dim3(256), 0, stream>>>(x, A);
    k_gemm<<<dim3(448), dim3(512), 0, stream>>>(A, Bt, P, agg, xb2, conv_b);
    k_edge<<<dim3(N_EDGES / 4), dim3(256), 0, stream>>>(ei, ea, P, xb2, agg);
    k_pool<<<dim3(N_NODES / 4), dim3(256), 0, stream>>>(agg, batch, psum, pcnt);
    k_head<<<dim3(N_GRAPHS), dim3(256), 0, stream>>>(psum, pcnt, fw1, fb1, fw2, fb2, fw3, fb3, fw4, fb4, out);
}

// Round 8
// 189.223 us; speedup vs baseline: 1.3087x; 1.0996x over previous
//
#include <hip/hip_runtime.h>
#include <hip/hip_bf16.h>
#include <stdint.h>

// Problem constants
#define N_NODES 8192
#define N_EDGES 16384
#define N_GRAPHS 512
#define IN_DIM 235
#define H_DIM 64
#define ED_DIM 52
#define HID1 128          // edge-MLP hidden width (W1 rows)
#define KP 256            // K padded 235 -> 256 for MFMA tiling
#define NB 3328           // H_DIM * ED_DIM = P column count (c = h*52 + d)
#define NBP 3584          // padded to 14 x 256 tiles (rows 3456..3583 zero)

// k_prep grid partition
#define BT_BLOCKS 940     // 235 i x 4 h-groups
#define EXT_BLOCKS 128
#define ZERO_BLOCKS 16
#define PREP_GRID (BT_BLOCKS + EXT_BLOCKS + ZERO_BLOCKS + N_NODES)

typedef __bf16 bf16x8 __attribute__((ext_vector_type(8)));
typedef float f32x4 __attribute__((ext_vector_type(4)));

static __device__ inline unsigned short f2bf(float f) {
    union { float f; unsigned u; } v; v.f = f;
    unsigned r = v.u + 0x7FFFu + ((v.u >> 16) & 1u);   // RNE
    return (unsigned short)(r >> 16);
}

// ---------------------------------------------------------------------------
// K_PREP: fused pre-GEMM work, one dispatch (was 2 memsets + 3 kernels):
//  blocks [0,940):           Bt live cols   (edge-MLP compose, h-major cols)
//  blocks [940,1068):        ext cols       (root / composed bias bc)
//  blocks [1068,1084):       Bt pad zeroing (cols 235..255 all rows; rows 3456+)
//  blocks [1084,9276):       A = bf16(x) zero-padded
// No intra-kernel deps between branches (disjoint outputs).
__global__ __launch_bounds__(256) void k_prep(const float* __restrict__ x,
                                              const float* __restrict__ W1,
                                              const float* __restrict__ W2,
                                              const float* __restrict__ b1,
                                              const float* __restrict__ b2,
                                              const float* __restrict__ root,
                                              unsigned short* __restrict__ A,
                                              unsigned short* __restrict__ Bt) {
    __shared__ float w1s[ED_DIM * 132];       // [d][k] padded, 27.5 KB
    __shared__ float w2s[16 * 132];           // [hh][k] padded, 8.4 KB
    const int bx = blockIdx.x;
    const int t = threadIdx.x;

    if (bx < BT_BLOCKS) {
        // ---- build_bt: Bt[c=(h*52+d)][i] = sum_k W2[(i*64+h)*128+k]*W1[k*52+d]
        // Thread (hh=t&15, dq=t>>4): d in {dq, dq+16, dq+32, dq+48} & [0,52).
        // w1 read: 4 distinct rows/wave at start banks 4*dq (disjoint broadcast
        // groups) -> conflict-free; w2 read: hh*132 -> 2-way (free).
        const int i = bx >> 2;                // 0..234
        const int by = bx & 3;                // h base by*16
        for (int j = t; j < ED_DIM * HID1; j += 256) {
            const int k = j / ED_DIM, d = j - k * ED_DIM;   // j linear in W1
            w1s[d * 132 + k] = W1[j];
        }
        const float* w2src = W2 + ((size_t)i * 64 + by * 16) * HID1;
        for (int j = t; j < 16 * HID1; j += 256) w2s[(j >> 7) * 132 + (j & 127)] = w2src[j];
        __syncthreads();
        const int hh = t & 15, dq = t >> 4;
        const float4* w2v = (const float4*)&w2s[hh * 132];
        #pragma unroll
        for (int m = 0; m < 4; ++m) {
            const int d = dq + m * 16;
            if (d >= ED_DIM) break;
            const float4* w1v = (const float4*)&w1s[d * 132];
            float acc = 0.f;
            #pragma unroll
            for (int k4 = 0; k4 < HID1 / 4; ++k4) {
                const float4 a = w1v[k4], b = w2v[k4];
                acc += a.x * b.x + a.y * b.y + a.z * b.z + a.w * b.w;
            }
            const int p = (by * 16 + hh) * ED_DIM + d;
            Bt[(size_t)p * KP + i] = f2bf(acc);
        }
    } else if (bx < BT_BLOCKS + EXT_BLOCKS) {
        // ---- ext cols: 3328+j (j<64) = root[:,j]; 3392+j = bc[:,j-64]
        const int j = bx - BT_BLOCKS;         // 0..127
        const int i = t;                      // 0..255
        if (i < IN_DIM) {
            float v;
            if (j < 64) {
                v = root[i * H_DIM + j];
            } else {
                const int jj = i * H_DIM + (j - 64);
                float acc = b2[jj];
                const float* w = W2 + (size_t)jj * HID1;
                #pragma unroll 8
                for (int k = 0; k < HID1; ++k) acc += w[k] * b1[k];
                v = acc;
            }
            Bt[(size_t)(NB + j) * KP + i] = f2bf(v);
        }
    } else if (bx < BT_BLOCKS + EXT_BLOCKS + ZERO_BLOCKS) {
        // ---- Bt pad zeroing: region1 rows 0..3583 cols 235..255 (3584*21),
        //                      region2 rows 3456..3583 cols 0..234 (128*235)
        const int z = bx - BT_BLOCKS - EXT_BLOCKS;
        const int R1 = NBP * 21;
        const int TOT = R1 + 128 * IN_DIM;
        for (int idx = z * 256 + t; idx < TOT; idx += ZERO_BLOCKS * 256) {
            size_t off;
            if (idx < R1) {
                const int r = idx / 21, c = IN_DIM + idx - (idx / 21) * 21;
                off = (size_t)r * KP + c;
            } else {
                const int k = idx - R1;
                const int r = 3456 + k / IN_DIM, c = k - (k / IN_DIM) * IN_DIM;
                off = (size_t)r * KP + c;
            }
            Bt[off] = 0;
        }
    } else {
        // ---- A build: x (fp32) -> A (bf16 [8192,256], cols >=235 zero)
        const int j = (bx - BT_BLOCKS - EXT_BLOCKS - ZERO_BLOCKS) * 256 + t;
        const int n = j >> 8, i = j & 255;
        A[j] = (i < IN_DIM) ? f2bf(x[n * IN_DIM + i]) : (unsigned short)0;
    }
}

// ---------------------------------------------------------------------------
// K2: [8192,256] x [256,3584] GEMM, 256x256 tiles (512 thr, 8 waves, each
// 128x64). 1-D grid of 448 with XCD-aware remap (lin%8 = XCD heuristic):
// XCD x owns m-tiles {x, x+8, x+16, x+24} x all 14 n-tiles -> per-XCD working
// set 0.5 MB A + 1.8 MB Bt < 4 MB L2. Prefetch-after-barrier dbuf, XOR source
// swizzle, swapped MFMA operands (transposed D -> packed row-major stores).
// n-tile 13 = ext tile: cols 3328..3391 -> agg(+conv_b), 3392..3455 -> xb2.
__global__ __launch_bounds__(512, 2) void k_gemm(const unsigned short* __restrict__ A,
                                                 const unsigned short* __restrict__ Bt,
                                                 unsigned short* __restrict__ P,
                                                 float* __restrict__ agg,
                                                 float* __restrict__ xb2,
                                                 const float* __restrict__ conv_b) {
    __shared__ unsigned short As[2 * 256 * 32];   // 32 KB
    __shared__ unsigned short Bs[2 * 256 * 32];   // 32 KB
    const int t = threadIdx.x;
    const int lin = blockIdx.x;                   // 0..447
    const int xcd = lin & 7, bi = lin >> 3;       // 56 blocks per XCD
    const int mt = (bi / 14) * 8 + xcd;           // 0..31
    const int nt = bi % 14;                       // 0..13
    const int m0 = mt * 256, n0 = nt * 256;
    const int wid = t >> 6, lane = t & 63;
    const int wm = wid & 1;          // 0..1 : 128-row half
    const int wn = wid >> 1;         // 0..3 : 64-col quarter
    const int q = lane >> 4, r16 = lane & 15;

    f32x4 acc[8][4] = {};

    auto stage = [&](int k0, int buf) {
        #pragma unroll
        for (int r = 0; r < 2; ++r) {
            const int idx = r * 512 + t;              // 0..1023 physical 16B slots
            const int row = idx >> 2;                 // 0..255
            const int lgrp = ((idx & 3) ^ ((row >> 1) & 3)) * 8;  // logical k-chunk
            const unsigned short* ga = &A[(size_t)(m0 + row) * KP + k0 + lgrp];
            const unsigned short* gb = &Bt[(size_t)(n0 + row) * KP + k0 + lgrp];
            char* la = (char*)As + buf * 16384 + r * 8192 + wid * 1024;
            char* lb = (char*)Bs + buf * 16384 + r * 8192 + wid * 1024;
            __builtin_amdgcn_global_load_lds(
                (const __attribute__((address_space(1))) unsigned int*)ga,
                (__attribute__((address_space(3))) unsigned int*)la, 16, 0, 0);
            __builtin_amdgcn_global_load_lds(
                (const __attribute__((address_space(1))) unsigned int*)gb,
                (__attribute__((address_space(3))) unsigned int*)lb, 16, 0, 0);
        }
    };

    stage(0, 0);
    const int pcq = (q ^ ((r16 >> 1) & 3)) * 8;       // physical chunk for logical q
    #pragma unroll
    for (int it = 0; it < 8; ++it) {
        __syncthreads();                              // drains prefetch for buf[it&1]
        if (it < 7) stage((it + 1) * 32, (it + 1) & 1);
        const int bo = (it & 1) * 8192;               // buffer offset in shorts
        bf16x8 af[8], bfr[4];
        #pragma unroll
        for (int mi = 0; mi < 8; ++mi)
            af[mi] = *(const bf16x8*)(&As[bo + (wm * 128 + mi * 16 + r16) * 32 + pcq]);
        #pragma unroll
        for (int ni = 0; ni < 4; ++ni)
            bfr[ni] = *(const bf16x8*)(&Bs[bo + (wn * 64 + ni * 16 + r16) * 32 + pcq]);
        #pragma unroll
        for (int mi = 0; mi < 8; ++mi)
            #pragma unroll
            for (int ni = 0; ni < 4; ++ni)
                acc[mi][ni] = __builtin_amdgcn_mfma_f32_16x16x32_bf16(
                    bfr[ni], af[mi], acc[mi][ni], 0, 0, 0);   // transposed D
    }

    // Transposed D: lane (q,r16) holds rows m = mi*16+r16, cols n = ni*16+q*4..+3
    if (n0 < NB) {
        #pragma unroll
        for (int mi = 0; mi < 8; ++mi)
            #pragma unroll
            for (int ni = 0; ni < 4; ++ni) {
                const int row = m0 + wm * 128 + mi * 16 + r16;
                const int col = n0 + wn * 64 + ni * 16 + q * 4;
                union { unsigned short us[4]; uint2 u2; } pk;
                #pragma unroll
                for (int rr = 0; rr < 4; ++rr) pk.us[rr] = f2bf(acc[mi][ni][rr]);
                *(uint2*)(&P[(size_t)row * NB + col]) = pk.u2;
            }
    } else if (wn < 2) {
        #pragma unroll
        for (int mi = 0; mi < 8; ++mi)
            #pragma unroll
            for (int ni = 0; ni < 4; ++ni) {
                const int row = m0 + wm * 128 + mi * 16 + r16;
                const int cl = ni * 16 + q * 4;       // 0..63 within the half
                if (wn == 0) {
                    const float4 cb = *(const float4*)&conv_b[cl];
                    float4 v;
                    v.x = acc[mi][ni][0] + cb.x; v.y = acc[mi][ni][1] + cb.y;
                    v.z = acc[mi][ni][2] + cb.z; v.w = acc[mi][ni][3] + cb.w;
                    *(float4*)(&agg[row * H_DIM + cl]) = v;
                } else {
                    float4 v;
                    v.x = acc[mi][ni][0]; v.y = acc[mi][ni][1];
                    v.z = acc[mi][ni][2]; v.w = acc[mi][ni][3];
                    *(float4*)(&xb2[row * H_DIM + cl]) = v;
                }
            }
    }
}

// ---------------------------------------------------------------------------
// K4: per edge (one wave, lane=h). h-major P: lane h's 52 d-values are 104
// contiguous bytes at P + s*3328 + h*52 -> 13 aligned uint2 loads, all in
// flight, fully coalesced across the wave.
__global__ __launch_bounds__(256) void k_edge(const int* __restrict__ ei,
                                              const float* __restrict__ ea,
                                              const unsigned short* __restrict__ P,
                                              const float* __restrict__ xb2,
                                              float* __restrict__ agg) {
    const int e = (blockIdx.x * 256 + threadIdx.x) >> 6;
    const int h = threadIdx.x & 63;
    if (e >= N_EDGES) return;
    const int s = ei[e], dst = ei[N_EDGES + e];
    const uint2* Pr = (const uint2*)(P + (size_t)s * NB + h * ED_DIM);
    const float4* ev = (const float4*)(ea + (size_t)e * ED_DIM);

    uint2 pv[13];
    #pragma unroll
    for (int j = 0; j < 13; ++j) pv[j] = Pr[j];
    float4 eav[13];
    #pragma unroll
    for (int j = 0; j < 13; ++j) eav[j] = ev[j];

    float acc = xb2[s * H_DIM + h];
    #pragma unroll
    for (int j = 0; j < 13; ++j) {
        union { unsigned u; float f; } a0, a1, b0, b1;
        a0.u = pv[j].x << 16; a1.u = pv[j].x & 0xffff0000u;
        b0.u = pv[j].y << 16; b1.u = pv[j].y & 0xffff0000u;
        acc += eav[j].x * a0.f + eav[j].y * a1.f
             + eav[j].z * b0.f + eav[j].w * b1.f;
    }
    atomicAdd(&agg[dst * H_DIM + h], acc);
}

// ---------------------------------------------------------------------------
// K_TAIL: fused relu + mean-pool + MLP head, one block per graph.
// batch is SORTED -> per-graph node range via binary search; no atomics,
// no psum/pcnt buffers or zeroing (was k_pool + k_head + memset).
__global__ __launch_bounds__(256) void k_tail(const float* __restrict__ agg,
                                              const int* __restrict__ batch,
                                              const float* __restrict__ fw1, const float* __restrict__ fb1,
                                              const float* __restrict__ fw2, const float* __restrict__ fb2,
                                              const float* __restrict__ fw3, const float* __restrict__ fb3,
                                              const float* __restrict__ fw4, const float* __restrict__ fb4,
                                              float* __restrict__ out) {
    __shared__ float red[256];
    __shared__ float sp[64], s1[128], s2[256], s3[128];
    const int g = blockIdx.x, t = threadIdx.x;

    // lower_bound(batch, g) and lower_bound(batch, g+1), redundantly per thread
    int lo = 0, hi = N_NODES;
    while (lo < hi) { const int mid = (lo + hi) >> 1; if (batch[mid] < g) lo = mid + 1; else hi = mid; }
    const int start = lo;
    hi = N_NODES;
    while (lo < hi) { const int mid = (lo + hi) >> 1; if (batch[mid] <= g) lo = mid + 1; else hi = mid; }
    const int end = lo;
    const float inv = 1.0f / fmaxf((float)(end - start), 1.0f);

    // relu + sum: thread (part=t>>6, h=t&63) strides nodes by 4
    float a = 0.f;
    for (int n = start + (t >> 6); n < end; n += 4)
        a += fmaxf(agg[n * H_DIM + (t & 63)], 0.f);
    red[t] = a;
    __syncthreads();
    if (t < 64) sp[t] = (red[t] + red[t + 64] + red[t + 128] + red[t + 192]) * inv;
    __syncthreads();

    if (t < 128) {
        float acc = fb1[t];
        const float* w = fw1 + t * 64;
        #pragma unroll 8
        for (int k = 0; k < 64; ++k) acc += sp[k] * w[k];
        s1[t] = fmaxf(acc, 0.f);
    }
    __syncthreads();
    {
        float acc = fb2[t];
        const float* w = fw2 + t * 128;
        #pragma unroll 8
        for (int k = 0; k < 128; ++k) acc += s1[k] * w[k];
        s2[t] = fmaxf(acc, 0.f);
    }
    __syncthreads();
    if (t < 128) {
        float acc = fb3[t];
        const float* w = fw3 + t * 256;
        #pragma unroll 8
        for (int k = 0; k < 256; ++k) acc += s2[k] * w[k];
        s3[t] = fmaxf(acc, 0.f);
    }
    __syncthreads();
    if (t < 64) {
        float p = s3[t] * fw4[t] + s3[t + 64] * fw4[t + 64];
        #pragma unroll
        for (int off = 32; off > 0; off >>= 1) p += __shfl_down(p, off);
        if (t == 0) out[g] = p + fb4[0];
    }
}

// ---------------------------------------------------------------------------
extern "C" void kernel_launch(void* const* d_in, const int* in_sizes, int n_in,
                              void* d_out, int out_size, void* d_ws, size_t ws_size,
                              hipStream_t stream) {
    const float* x      = (const float*)d_in[0];
    const int*   ei     = (const int*)d_in[1];
    const float* ea     = (const float*)d_in[2];
    const int*   batch  = (const int*)d_in[3];
    const float* W1     = (const float*)d_in[4];
    const float* b1     = (const float*)d_in[5];
    const float* W2     = (const float*)d_in[6];
    const float* b2     = (const float*)d_in[7];
    const float* root   = (const float*)d_in[8];
    const float* conv_b = (const float*)d_in[9];
    const float* fw1 = (const float*)d_in[10]; const float* fb1 = (const float*)d_in[11];
    const float* fw2 = (const float*)d_in[12]; const float* fb2 = (const float*)d_in[13];
    const float* fw3 = (const float*)d_in[14]; const float* fb3 = (const float*)d_in[15];
    const float* fw4 = (const float*)d_in[16]; const float* fb4 = (const float*)d_in[17];
    float* out = (float*)d_out;

    char* ws = (char*)d_ws;
    // workspace layout (16B-aligned), total ~64.8 MB
    unsigned short* A   = (unsigned short*)(ws);             // 8192*256*2   = 4,194,304
    unsigned short* Bt  = (unsigned short*)(ws + 4194304);   // 3584*256*2   = 1,835,008
    unsigned short* P   = (unsigned short*)(ws + 6029312);   // 8192*3328*2  = 54,525,952
    float* agg  = (float*)(ws + 60555264);                   // 8192*64*4    = 2,097,152
    float* xb2  = (float*)(ws + 62652416);                   // 8192*64*4    = 2,097,152

    k_prep<<<dim3(PREP_GRID), dim3(256), 0, stream>>>(x, W1, W2, b1, b2, root, A, Bt);
    k_gemm<<<dim3(448), dim3(512), 0, stream>>>(A, Bt, P, agg, xb2, conv_b);
    k_edge<<<dim3(N_EDGES / 4), dim3(256), 0, stream>>>(ei, ea, P, xb2, agg);
    k_tail<<<dim3(N_GRAPHS), dim3(256), 0, stream>>>(agg, batch, fw1, fb1, fw2, fb2, fw3, fb3, fw4, fb4, out);
}

// Round 9
// 187.781 us; speedup vs baseline: 1.3188x; 1.0077x over previous
//
#include <hip/hip_runtime.h>
#include <hip/hip_bf16.h>
#include <stdint.h>

// Problem constants
#define N_NODES 8192
#define N_EDGES 16384
#define N_GRAPHS 512
#define IN_DIM 235
#define H_DIM 64
#define ED_DIM 52
#define HID1 128          // edge-MLP hidden width (W1 rows)
#define KP 256            // K padded 235 -> 256 for MFMA tiling
#define NB 3328           // H_DIM * ED_DIM = P column count (c = h*52 + d)
#define NBP 3584          // padded to 14 x 256 tiles (rows 3456..3583 zero)

// k_prep grid partition
#define BT_BLOCKS 940     // 235 i x 4 h-groups
#define EXT_BLOCKS 128
#define ZERO_BLOCKS 16
#define PREP_GRID (BT_BLOCKS + EXT_BLOCKS + ZERO_BLOCKS + N_NODES)

typedef __bf16 bf16x8 __attribute__((ext_vector_type(8)));
typedef float f32x4 __attribute__((ext_vector_type(4)));

static __device__ inline unsigned short f2bf(float f) {
    union { float f; unsigned u; } v; v.f = f;
    unsigned r = v.u + 0x7FFFu + ((v.u >> 16) & 1u);   // RNE
    return (unsigned short)(r >> 16);
}

// ---------------------------------------------------------------------------
// K_PREP: fused pre-GEMM work, one dispatch:
//  blocks [0,940):           Bt live cols   (edge-MLP compose, h-major cols)
//  blocks [940,1068):        ext cols       (root / composed bias bc)
//  blocks [1068,1084):       Bt pad zeroing
//  blocks [1084,9276):       A = bf16(x) zero-padded
__global__ __launch_bounds__(256) void k_prep(const float* __restrict__ x,
                                              const float* __restrict__ W1,
                                              const float* __restrict__ W2,
                                              const float* __restrict__ b1,
                                              const float* __restrict__ b2,
                                              const float* __restrict__ root,
                                              unsigned short* __restrict__ A,
                                              unsigned short* __restrict__ Bt) {
    __shared__ float w1s[ED_DIM * 132];       // [d][k] padded, 27.5 KB
    __shared__ float w2s[16 * 132];           // [hh][k] padded, 8.4 KB
    const int bx = blockIdx.x;
    const int t = threadIdx.x;

    if (bx < BT_BLOCKS) {
        // Bt[c=(h*52+d)][i] = sum_k W2[(i*64+h)*128+k]*W1[k*52+d]
        // Thread (hh=t&15, dq=t>>4): d in {dq, dq+16, dq+32, dq+48} & [0,52).
        // w1 read: 4 distinct rows/wave at disjoint start banks -> conflict-free;
        // w2 read: hh*132 -> 2-way (free).
        const int i = bx >> 2;                // 0..234
        const int by = bx & 3;                // h base by*16
        for (int j = t; j < ED_DIM * HID1; j += 256) {
            const int k = j / ED_DIM, d = j - k * ED_DIM;   // j linear in W1
            w1s[d * 132 + k] = W1[j];
        }
        const float* w2src = W2 + ((size_t)i * 64 + by * 16) * HID1;
        for (int j = t; j < 16 * HID1; j += 256) w2s[(j >> 7) * 132 + (j & 127)] = w2src[j];
        __syncthreads();
        const int hh = t & 15, dq = t >> 4;
        const float4* w2v = (const float4*)&w2s[hh * 132];
        #pragma unroll
        for (int m = 0; m < 4; ++m) {
            const int d = dq + m * 16;
            if (d >= ED_DIM) break;
            const float4* w1v = (const float4*)&w1s[d * 132];
            float acc = 0.f;
            #pragma unroll
            for (int k4 = 0; k4 < HID1 / 4; ++k4) {
                const float4 a = w1v[k4], b = w2v[k4];
                acc += a.x * b.x + a.y * b.y + a.z * b.z + a.w * b.w;
            }
            const int p = (by * 16 + hh) * ED_DIM + d;
            Bt[(size_t)p * KP + i] = f2bf(acc);
        }
    } else if (bx < BT_BLOCKS + EXT_BLOCKS) {
        // ext cols: 3328+j (j<64) = root[:,j]; 3392+j = bc[:,j-64]
        const int j = bx - BT_BLOCKS;         // 0..127
        const int i = t;                      // 0..255
        if (i < IN_DIM) {
            float v;
            if (j < 64) {
                v = root[i * H_DIM + j];
            } else {
                const int jj = i * H_DIM + (j - 64);
                float acc = b2[jj];
                const float* w = W2 + (size_t)jj * HID1;
                #pragma unroll 8
                for (int k = 0; k < HID1; ++k) acc += w[k] * b1[k];
                v = acc;
            }
            Bt[(size_t)(NB + j) * KP + i] = f2bf(v);
        }
    } else if (bx < BT_BLOCKS + EXT_BLOCKS + ZERO_BLOCKS) {
        // Bt pad zeroing: rows 0..3583 cols 235..255; rows 3456..3583 cols 0..234
        const int z = bx - BT_BLOCKS - EXT_BLOCKS;
        const int R1 = NBP * 21;
        const int TOT = R1 + 128 * IN_DIM;
        for (int idx = z * 256 + t; idx < TOT; idx += ZERO_BLOCKS * 256) {
            size_t off;
            if (idx < R1) {
                const int r = idx / 21, c = IN_DIM + idx - (idx / 21) * 21;
                off = (size_t)r * KP + c;
            } else {
                const int k = idx - R1;
                const int r = 3456 + k / IN_DIM, c = k - (k / IN_DIM) * IN_DIM;
                off = (size_t)r * KP + c;
            }
            Bt[off] = 0;
        }
    } else {
        // A build: x (fp32) -> A (bf16 [8192,256], cols >=235 zero)
        const int j = (bx - BT_BLOCKS - EXT_BLOCKS - ZERO_BLOCKS) * 256 + t;
        const int n = j >> 8, i = j & 255;
        A[j] = (i < IN_DIM) ? f2bf(x[n * IN_DIM + i]) : (unsigned short)0;
    }
}

// ---------------------------------------------------------------------------
// K2: [8192,256] x [256,3584] GEMM, 256x256 block tiles, now 1024 threads =
// 16 waves each computing 64x64 (4x4 MFMA). acc drops 128->64 f32/thread so
// total VGPR fits the 128 cap -> 4 waves/SIMD (was 2) = 2x latency-hiding TLP
// at identical tile size / traffic / LDS (64 KB dbuf, 1 block/CU).
// XCD-aware remap, prefetch-after-barrier dbuf, XOR source swizzle, swapped
// MFMA operands (transposed D -> packed row-major stores).
// n-tile 13 = ext tile: cols 3328..3391 -> agg(+conv_b), 3392..3455 -> xb2.
__global__ __launch_bounds__(1024, 4) void k_gemm(const unsigned short* __restrict__ A,
                                                  const unsigned short* __restrict__ Bt,
                                                  unsigned short* __restrict__ P,
                                                  float* __restrict__ agg,
                                                  float* __restrict__ xb2,
                                                  const float* __restrict__ conv_b) {
    __shared__ unsigned short As[2 * 256 * 32];   // 32 KB
    __shared__ unsigned short Bs[2 * 256 * 32];   // 32 KB
    const int t = threadIdx.x;
    const int lin = blockIdx.x;                   // 0..447
    const int xcd = lin & 7, bi = lin >> 3;       // 56 blocks per XCD
    const int mt = (bi / 14) * 8 + xcd;           // 0..31
    const int nt = bi % 14;                       // 0..13
    const int m0 = mt * 256, n0 = nt * 256;
    const int wid = t >> 6, lane = t & 63;
    const int wm = wid & 3;          // 0..3 : 64-row quarter
    const int wn = wid >> 2;         // 0..3 : 64-col quarter
    const int q = lane >> 4, r16 = lane & 15;

    f32x4 acc[4][4] = {};

    auto stage = [&](int k0, int buf) {
        const int idx = t;                        // 0..1023, one 16B slot each
        const int row = idx >> 2;                 // 0..255
        const int lgrp = ((idx & 3) ^ ((row >> 1) & 3)) * 8;  // logical k-chunk
        const unsigned short* ga = &A[(size_t)(m0 + row) * KP + k0 + lgrp];
        const unsigned short* gb = &Bt[(size_t)(n0 + row) * KP + k0 + lgrp];
        char* la = (char*)As + buf * 16384 + wid * 1024;
        char* lb = (char*)Bs + buf * 16384 + wid * 1024;
        __builtin_amdgcn_global_load_lds(
            (const __attribute__((address_space(1))) unsigned int*)ga,
            (__attribute__((address_space(3))) unsigned int*)la, 16, 0, 0);
        __builtin_amdgcn_global_load_lds(
            (const __attribute__((address_space(1))) unsigned int*)gb,
            (__attribute__((address_space(3))) unsigned int*)lb, 16, 0, 0);
    };

    stage(0, 0);
    const int pcq = (q ^ ((r16 >> 1) & 3)) * 8;       // physical chunk for logical q
    #pragma unroll
    for (int it = 0; it < 8; ++it) {
        __syncthreads();                              // drains prefetch for buf[it&1]
        if (it < 7) stage((it + 1) * 32, (it + 1) & 1);
        const int bo = (it & 1) * 8192;               // buffer offset in shorts
        bf16x8 af[4], bfr[4];
        #pragma unroll
        for (int mi = 0; mi < 4; ++mi)
            af[mi] = *(const bf16x8*)(&As[bo + (wm * 64 + mi * 16 + r16) * 32 + pcq]);
        #pragma unroll
        for (int ni = 0; ni < 4; ++ni)
            bfr[ni] = *(const bf16x8*)(&Bs[bo + (wn * 64 + ni * 16 + r16) * 32 + pcq]);
        #pragma unroll
        for (int mi = 0; mi < 4; ++mi)
            #pragma unroll
            for (int ni = 0; ni < 4; ++ni)
                acc[mi][ni] = __builtin_amdgcn_mfma_f32_16x16x32_bf16(
                    bfr[ni], af[mi], acc[mi][ni], 0, 0, 0);   // transposed D
    }

    // Transposed D: lane (q,r16) holds rows m = mi*16+r16, cols n = ni*16+q*4..+3
    if (n0 < NB) {
        #pragma unroll
        for (int mi = 0; mi < 4; ++mi)
            #pragma unroll
            for (int ni = 0; ni < 4; ++ni) {
                const int row = m0 + wm * 64 + mi * 16 + r16;
                const int col = n0 + wn * 64 + ni * 16 + q * 4;
                union { unsigned short us[4]; uint2 u2; } pk;
                #pragma unroll
                for (int rr = 0; rr < 4; ++rr) pk.us[rr] = f2bf(acc[mi][ni][rr]);
                *(uint2*)(&P[(size_t)row * NB + col]) = pk.u2;
            }
    } else if (wn < 2) {
        #pragma unroll
        for (int mi = 0; mi < 4; ++mi)
            #pragma unroll
            for (int ni = 0; ni < 4; ++ni) {
                const int row = m0 + wm * 64 + mi * 16 + r16;
                const int cl = ni * 16 + q * 4;       // 0..63 within the half
                if (wn == 0) {
                    const float4 cb = *(const float4*)&conv_b[cl];
                    float4 v;
                    v.x = acc[mi][ni][0] + cb.x; v.y = acc[mi][ni][1] + cb.y;
                    v.z = acc[mi][ni][2] + cb.z; v.w = acc[mi][ni][3] + cb.w;
                    *(float4*)(&agg[row * H_DIM + cl]) = v;
                } else {
                    float4 v;
                    v.x = acc[mi][ni][0]; v.y = acc[mi][ni][1];
                    v.z = acc[mi][ni][2]; v.w = acc[mi][ni][3];
                    *(float4*)(&xb2[row * H_DIM + cl]) = v;
                }
            }
    }
}

// ---------------------------------------------------------------------------
// K4: per edge (one wave, lane=h). h-major P: lane h's 52 d-values are 104
// contiguous bytes at P + s*3328 + h*52 -> 13 aligned uint2 loads, all in
// flight, fully coalesced across the wave.
__global__ __launch_bounds__(256) void k_edge(const int* __restrict__ ei,
                                              const float* __restrict__ ea,
                                              const unsigned short* __restrict__ P,
                                              const float* __restrict__ xb2,
                                              float* __restrict__ agg) {
    const int e = (blockIdx.x * 256 + threadIdx.x) >> 6;
    const int h = threadIdx.x & 63;
    if (e >= N_EDGES) return;
    const int s = ei[e], dst = ei[N_EDGES + e];
    const uint2* Pr = (const uint2*)(P + (size_t)s * NB + h * ED_DIM);
    const float4* ev = (const float4*)(ea + (size_t)e * ED_DIM);

    uint2 pv[13];
    #pragma unroll
    for (int j = 0; j < 13; ++j) pv[j] = Pr[j];
    float4 eav[13];
    #pragma unroll
    for (int j = 0; j < 13; ++j) eav[j] = ev[j];

    float acc = xb2[s * H_DIM + h];
    #pragma unroll
    for (int j = 0; j < 13; ++j) {
        union { unsigned u; float f; } a0, a1, b0, b1;
        a0.u = pv[j].x << 16; a1.u = pv[j].x & 0xffff0000u;
        b0.u = pv[j].y << 16; b1.u = pv[j].y & 0xffff0000u;
        acc += eav[j].x * a0.f + eav[j].y * a1.f
             + eav[j].z * b0.f + eav[j].w * b1.f;
    }
    atomicAdd(&agg[dst * H_DIM + h], acc);
}

// ---------------------------------------------------------------------------
// K_TAIL: fused relu + mean-pool + MLP head, one block per graph.
// batch is SORTED -> per-graph node range via binary search; no atomics.
__global__ __launch_bounds__(256) void k_tail(const float* __restrict__ agg,
                                              const int* __restrict__ batch,
                                              const float* __restrict__ fw1, const float* __restrict__ fb1,
                                              const float* __restrict__ fw2, const float* __restrict__ fb2,
                                              const float* __restrict__ fw3, const float* __restrict__ fb3,
                                              const float* __restrict__ fw4, const float* __restrict__ fb4,
                                              float* __restrict__ out) {
    __shared__ float red[256];
    __shared__ float sp[64], s1[128], s2[256], s3[128];
    const int g = blockIdx.x, t = threadIdx.x;

    int lo = 0, hi = N_NODES;
    while (lo < hi) { const int mid = (lo + hi) >> 1; if (batch[mid] < g) lo = mid + 1; else hi = mid; }
    const int start = lo;
    hi = N_NODES;
    while (lo < hi) { const int mid = (lo + hi) >> 1; if (batch[mid] <= g) lo = mid + 1; else hi = mid; }
    const int end = lo;
    const float inv = 1.0f / fmaxf((float)(end - start), 1.0f);

    float a = 0.f;
    for (int n = start + (t >> 6); n < end; n += 4)
        a += fmaxf(agg[n * H_DIM + (t & 63)], 0.f);
    red[t] = a;
    __syncthreads();
    if (t < 64) sp[t] = (red[t] + red[t + 64] + red[t + 128] + red[t + 192]) * inv;
    __syncthreads();

    if (t < 128) {
        float acc = fb1[t];
        const float* w = fw1 + t * 64;
        #pragma unroll 8
        for (int k = 0; k < 64; ++k) acc += sp[k] * w[k];
        s1[t] = fmaxf(acc, 0.f);
    }
    __syncthreads();
    {
        float acc = fb2[t];
        const float* w = fw2 + t * 128;
        #pragma unroll 8
        for (int k = 0; k < 128; ++k) acc += s1[k] * w[k];
        s2[t] = fmaxf(acc, 0.f);
    }
    __syncthreads();
    if (t < 128) {
        float acc = fb3[t];
        const float* w = fw3 + t * 256;
        #pragma unroll 8
        for (int k = 0; k < 256; ++k) acc += s2[k] * w[k];
        s3[t] = fmaxf(acc, 0.f);
    }
    __syncthreads();
    if (t < 64) {
        float p = s3[t] * fw4[t] + s3[t + 64] * fw4[t + 64];
        #pragma unroll
        for (int off = 32; off > 0; off >>= 1) p += __shfl_down(p, off);
        if (t == 0) out[g] = p + fb4[0];
    }
}

// ---------------------------------------------------------------------------
extern "C" void kernel_launch(void* const* d_in, const int* in_sizes, int n_in,
                              void* d_out, int out_size, void* d_ws, size_t ws_size,
                              hipStream_t stream) {
    const float* x      = (const float*)d_in[0];
    const int*   ei     = (const int*)d_in[1];
    const float* ea     = (const float*)d_in[2];
    const int*   batch  = (const int*)d_in[3];
    const float* W1     = (const float*)d_in[4];
    const float* b1     = (const float*)d_in[5];
    const float* W2     = (const float*)d_in[6];
    const float* b2     = (const float*)d_in[7];
    const float* root   = (const float*)d_in[8];
    const float* conv_b = (const float*)d_in[9];
    const float* fw1 = (const float*)d_in[10]; const float* fb1 = (const float*)d_in[11];
    const float* fw2 = (const float*)d_in[12]; const float* fb2 = (const float*)d_in[13];
    const float* fw3 = (const float*)d_in[14]; const float* fb3 = (const float*)d_in[15];
    const float* fw4 = (const float*)d_in[16]; const float* fb4 = (const float*)d_in[17];
    float* out = (float*)d_out;

    char* ws = (char*)d_ws;
    // workspace layout (16B-aligned), total ~64.8 MB
    unsigned short* A   = (unsigned short*)(ws);             // 8192*256*2   = 4,194,304
    unsigned short* Bt  = (unsigned short*)(ws + 4194304);   // 3584*256*2   = 1,835,008
    unsigned short* P   = (unsigned short*)(ws + 6029312);   // 8192*3328*2  = 54,525,952
    float* agg  = (float*)(ws + 60555264);                   // 8192*64*4    = 2,097,152
    float* xb2  = (float*)(ws + 62652416);                   // 8192*64*4    = 2,097,152

    k_prep<<<dim3(PREP_GRID), dim3(256), 0, stream>>>(x, W1, W2, b1, b2, root, A, Bt);
    k_gemm<<<dim3(448), dim3(1024), 0, stream>>>(A, Bt, P, agg, xb2, conv_b);
    k_edge<<<dim3(N_EDGES / 4), dim3(256), 0, stream>>>(ei, ea, P, xb2, agg);
    k_tail<<<dim3(N_GRAPHS), dim3(256), 0, stream>>>(agg, batch, fw1, fb1, fw2, fb2, fw3, fb3, fw4, fb4, out);
}